// Round 4
// baseline (323.612 us; speedup 1.0000x reference)
//
#include <hip/hip_runtime.h>
#include <math.h>

#define NN   4096
#define DD   512
#define TWON 8192
#define KSLICE 4

using short8 = __attribute__((ext_vector_type(8))) short;
using f32x4  = __attribute__((ext_vector_type(4))) float;
typedef unsigned short u16;

__device__ __forceinline__ u16 f2bf(float f) {
    unsigned u = __float_as_uint(f);
    u += 0x7fffu + ((u >> 16) & 1u);
    return (u16)(u >> 16);
}
__device__ __forceinline__ float bf2f(u16 h) {
    return __uint_as_float(((unsigned)h) << 16);
}
__device__ __forceinline__ void gl16(const void* g, void* l) {
    __builtin_amdgcn_global_load_lds(
        (const __attribute__((address_space(1))) void*)g,
        (__attribute__((address_space(3))) void*)l, 16, 0, 0);
}
__device__ __forceinline__ f32x4 mfma16(short8 a, short8 b, f32x4 c) {
    return __builtin_amdgcn_mfma_f32_16x16x32_bf16(a, b, c, 0, 0, 0);
}

// ---------------- prep: b=[y;x] -> bhi/blo bf16 split + norms nb[8192]
__global__ __launch_bounds__(64)
void prep_k(const float* __restrict__ x, const float* __restrict__ y,
            u16* __restrict__ bhi, u16* __restrict__ blo, float* __restrict__ nb) {
    int r = blockIdx.x;           // 0..8191
    int l = threadIdx.x;          // 64
    const float* src = (r < NN) ? (y + (size_t)r * DD) : (x + (size_t)(r - NN) * DD);
    float4 v0 = *reinterpret_cast<const float4*>(src + l * 8);
    float4 v1 = *reinterpret_cast<const float4*>(src + l * 8 + 4);
    float e[8] = {v0.x, v0.y, v0.z, v0.w, v1.x, v1.y, v1.z, v1.w};
    float s = 0.f;
    short8 h, lo;
    #pragma unroll
    for (int q = 0; q < 8; ++q) {
        s += e[q] * e[q];
        u16 hq = f2bf(e[q]);
        h[q]  = (short)hq;
        lo[q] = (short)f2bf(e[q] - bf2f(hq));
    }
    *reinterpret_cast<short8*>(bhi + (size_t)r * DD + l * 8) = h;
    *reinterpret_cast<short8*>(blo + (size_t)r * DD + l * 8) = lo;
    #pragma unroll
    for (int off = 32; off; off >>= 1) s += __shfl_down(s, off);
    if (l == 0) nb[r] = s;
}

// ---------------- b2t: b2t[d][k] = k<N ? y[k][d] : -x[k-N][d]  (bf16, 512x8192)
// NOTE: reads the ORIGINAL f32 inputs (not bhi) — b2t aliases the bhi region,
// so reading bhi here would be a cross-block race (round-3 bug).
__global__ __launch_bounds__(256)
void b2t_k(const float* __restrict__ x, const float* __restrict__ y, u16* __restrict__ b2t) {
    __shared__ float tl[32][33];
    int k0 = blockIdx.x * 32, d0 = blockIdx.y * 32;
    int tx = threadIdx.x, ty = threadIdx.y;   // (32,8)
    const float* src = (k0 < NN) ? y : x;
    int row0 = (k0 < NN) ? k0 : (k0 - NN);
    #pragma unroll
    for (int j = 0; j < 4; ++j)
        tl[ty + 8 * j][tx] = src[(size_t)(row0 + ty + 8 * j) * DD + d0 + tx];
    __syncthreads();
    float sgn = (k0 < NN) ? 1.f : -1.f;
    #pragma unroll
    for (int j = 0; j < 4; ++j) {
        float v = tl[tx][ty + 8 * j] * sgn;
        b2t[(size_t)(d0 + ty + 8 * j) * TWON + k0 + tx] = f2bf(v);
    }
}

// ---------------- GEMM1: 3-term bf16 split MFMA + logits + fused partial stats
__global__ __launch_bounds__(256)
void gemm1_k(const u16* __restrict__ bhi, const u16* __restrict__ blo,
             const float* __restrict__ nb, float* __restrict__ L,
             float* __restrict__ rpm, float* __restrict__ rps,
             float* __restrict__ cpm, float* __restrict__ cps) {
    __shared__ unsigned char lds[65536]; // Ahi@0 Alo@16K Bhi@32K Blo@48K, each 128x64 bf16
    const int t = threadIdx.x;
    const int wave = t >> 6, lane = t & 63;
    const int i0 = blockIdx.y * 128, j0 = blockIdx.x * 128;
    const int wm = (wave >> 1) * 64, wn = (wave & 1) * 64;
    const u16* ahig = bhi + (size_t)NN * DD;  // x rows are b rows 4096..8191
    const u16* alog = blo + (size_t)NN * DD;
    f32x4 acc[4][4] = {};
    for (int k0 = 0; k0 < DD; k0 += 64) {
        __syncthreads();
        #pragma unroll
        for (int q = 0; q < 4; ++q) {
            const int dbase = (wave * 4 + q) * 1024;
            const int p  = dbase + lane * 16;
            const int r  = p >> 7;
            const int cb = (p & 127) ^ ((r & 7) << 4);
            const size_t offA = (size_t)(i0 + r) * DD + k0 + (cb >> 1);
            const size_t offB = (size_t)(j0 + r) * DD + k0 + (cb >> 1);
            gl16(ahig + offA, lds + dbase);
            gl16(alog + offA, lds + 16384 + dbase);
            gl16(bhi  + offB, lds + 32768 + dbase);
            gl16(blo  + offB, lds + 49152 + dbase);
        }
        asm volatile("s_waitcnt vmcnt(0)" ::: "memory");
        __syncthreads();
        #pragma unroll
        for (int kk = 0; kk < 2; ++kk) {
            short8 ah[4], al[4];
            #pragma unroll
            for (int m = 0; m < 4; ++m) {
                const int row = wm + m * 16 + (lane & 15);
                const int off = row * 128 + ((kk * 64 + (lane >> 4) * 16) ^ ((row & 7) << 4));
                ah[m] = *reinterpret_cast<const short8*>(lds + off);
                al[m] = *reinterpret_cast<const short8*>(lds + 16384 + off);
            }
            #pragma unroll
            for (int n = 0; n < 4; ++n) {
                const int row = wn + n * 16 + (lane & 15);
                const int off = row * 128 + ((kk * 64 + (lane >> 4) * 16) ^ ((row & 7) << 4));
                short8 bh = *reinterpret_cast<const short8*>(lds + 32768 + off);
                short8 bl = *reinterpret_cast<const short8*>(lds + 49152 + off);
                #pragma unroll
                for (int m = 0; m < 4; ++m) {
                    acc[m][n] = mfma16(ah[m], bh, acc[m][n]);
                    acc[m][n] = mfma16(ah[m], bl, acc[m][n]);
                    acc[m][n] = mfma16(al[m], bh, acc[m][n]);
                }
            }
        }
    }
    // ---- transform acc -> logits, store L
    float nbj[4];
    #pragma unroll
    for (int n = 0; n < 4; ++n) nbj[n] = nb[j0 + wn + n * 16 + (lane & 15)];
    #pragma unroll
    for (int m = 0; m < 4; ++m) {
        #pragma unroll
        for (int r4 = 0; r4 < 4; ++r4) {
            const int i = i0 + wm + m * 16 + (lane >> 4) * 4 + r4;
            const float nxi = nb[NN + i];
            #pragma unroll
            for (int n = 0; n < 4; ++n) {
                const int j = j0 + wn + n * 16 + (lane & 15);
                float sq = nxi + nbj[n] - 2.0f * acc[m][n][r4];
                float lg = -10.0f * sqrtf(fmaxf(sq, 1e-12f));
                if (j == i + NN) lg = -1e7f;
                acc[m][n][r4] = lg;
                L[(size_t)i * TWON + j] = lg;
            }
        }
    }
    // ---- per-tile row partials (max+sum over this block's 128 cols)
    float rmx[16], rsm[16];
    #pragma unroll
    for (int m = 0; m < 4; ++m)
        #pragma unroll
        for (int r4 = 0; r4 < 4; ++r4) {
            const int idx = m * 4 + r4;
            float M = fmaxf(fmaxf(acc[m][0][r4], acc[m][1][r4]),
                            fmaxf(acc[m][2][r4], acc[m][3][r4]));
            float S = __expf(acc[m][0][r4] - M) + __expf(acc[m][1][r4] - M) +
                      __expf(acc[m][2][r4] - M) + __expf(acc[m][3][r4] - M);
            rmx[idx] = M; rsm[idx] = S;
        }
    #pragma unroll
    for (int off = 1; off < 16; off <<= 1) {
        #pragma unroll
        for (int idx = 0; idx < 16; ++idx) {
            float om = __shfl_xor(rmx[idx], off);
            float os = __shfl_xor(rsm[idx], off);
            float M = fmaxf(rmx[idx], om);
            rsm[idx] = rsm[idx] * __expf(rmx[idx] - M) + os * __expf(om - M);
            rmx[idx] = M;
        }
    }
    // ---- per-tile col partials (max+sum over this block's 128 rows)
    float cmx[4], csm[4];
    #pragma unroll
    for (int n = 0; n < 4; ++n) {
        float M = -3.0e38f;
        #pragma unroll
        for (int m = 0; m < 4; ++m)
            #pragma unroll
            for (int r4 = 0; r4 < 4; ++r4) M = fmaxf(M, acc[m][n][r4]);
        float S = 0.f;
        #pragma unroll
        for (int m = 0; m < 4; ++m)
            #pragma unroll
            for (int r4 = 0; r4 < 4; ++r4) S += __expf(acc[m][n][r4] - M);
        cmx[n] = M; csm[n] = S;
    }
    #pragma unroll
    for (int off = 16; off < 64; off <<= 1) {
        #pragma unroll
        for (int n = 0; n < 4; ++n) {
            float om = __shfl_xor(cmx[n], off);
            float os = __shfl_xor(csm[n], off);
            float M = fmaxf(cmx[n], om);
            csm[n] = csm[n] * __expf(cmx[n] - M) + os * __expf(om - M);
            cmx[n] = M;
        }
    }
    // ---- combine across waves via LDS, write per-tile partials
    __syncthreads();
    float* red = reinterpret_cast<float*>(lds);   // rows [0..512), cols [512..1024)
    if ((lane & 15) == 0) {
        #pragma unroll
        for (int m = 0; m < 4; ++m)
            #pragma unroll
            for (int r4 = 0; r4 < 4; ++r4) {
                const int r = wm + m * 16 + (lane >> 4) * 4 + r4;
                red[((wave & 1) * 128 + r) * 2]     = rmx[m * 4 + r4];
                red[((wave & 1) * 128 + r) * 2 + 1] = rsm[m * 4 + r4];
            }
    }
    if (lane < 16) {
        #pragma unroll
        for (int n = 0; n < 4; ++n) {
            const int c = wn + n * 16 + lane;
            red[512 + ((wave >> 1) * 128 + c) * 2]     = cmx[n];
            red[512 + ((wave >> 1) * 128 + c) * 2 + 1] = csm[n];
        }
    }
    __syncthreads();
    if (t < 128) {
        const int r = t;
        float m0 = red[r * 2], s0 = red[r * 2 + 1];
        float m1 = red[(128 + r) * 2], s1 = red[(128 + r) * 2 + 1];
        float M = fmaxf(m0, m1);
        float S = s0 * __expf(m0 - M) + s1 * __expf(m1 - M);
        rpm[(size_t)blockIdx.x * NN + i0 + r] = M;
        rps[(size_t)blockIdx.x * NN + i0 + r] = S;
    } else if (t < 256) {
        const int c = t - 128;
        float m0 = red[512 + c * 2], s0 = red[512 + c * 2 + 1];
        float m1 = red[512 + (128 + c) * 2], s1 = red[512 + (128 + c) * 2 + 1];
        float M = fmaxf(m0, m1);
        float S = s0 * __expf(m0 - M) + s1 * __expf(m1 - M);
        cpm[(size_t)blockIdx.y * TWON + j0 + c] = M;
        cps[(size_t)blockIdx.y * TWON + j0 + c] = S;
    }
}

// ---------------- combine row partials (64 j-tiles) -> rm, rrs
__global__ __launch_bounds__(256)
void row_comb_k(const float* __restrict__ rpm, const float* __restrict__ rps,
                float* __restrict__ rm, float* __restrict__ rrs) {
    int i = blockIdx.x * 256 + threadIdx.x;
    float M = -3.0e38f;
    for (int tt = 0; tt < TWON / 128; ++tt) M = fmaxf(M, rpm[(size_t)tt * NN + i]);
    float S = 0.f;
    for (int tt = 0; tt < TWON / 128; ++tt)
        S += rps[(size_t)tt * NN + i] * __expf(rpm[(size_t)tt * NN + i] - M);
    rm[i] = M; rrs[i] = rsqrtf(S);
}

// ---------------- combine col partials (32 i-tiles) -> cm, rcs
__global__ __launch_bounds__(256)
void col_comb_k(const float* __restrict__ cpm, const float* __restrict__ cps,
                float* __restrict__ cm, float* __restrict__ rcs) {
    int j = blockIdx.x * 256 + threadIdx.x;
    float M = -3.0e38f;
    for (int tt = 0; tt < NN / 128; ++tt) M = fmaxf(M, cpm[(size_t)tt * TWON + j]);
    float S = 0.f;
    for (int tt = 0; tt < NN / 128; ++tt)
        S += cps[(size_t)tt * TWON + j] * __expf(cpm[(size_t)tt * TWON + j] - M);
    cm[j] = M; rcs[j] = rsqrtf(S);
}

// ---------------- GEMM2: split-K, A from L (fused softmax transform, reg-staged
// double-buffered LDS), B frags straight from L2, partial outputs
__global__ __launch_bounds__(512)
void gemm2_k(const float* __restrict__ L, const u16* __restrict__ b2t,
             const float* __restrict__ rm, const float* __restrict__ rrs,
             const float* __restrict__ cm, const float* __restrict__ rcs,
             float* __restrict__ part) {
    __shared__ unsigned char lds[16384];   // 2 x (64x64 bf16 A tile, swizzled)
    const int t = threadIdx.x;
    const int wave = t >> 6, lane = t & 63;
    const int i0 = blockIdx.x * 64;
    const int kbase = blockIdx.y * (TWON / KSLICE);
    const int wn = wave * 64;
    const int ar = t >> 3;          // 0..63 staging row
    const int ac = (t & 7) * 8;     // staging col
    const float hrm = 0.5f * rm[i0 + ar];
    const float sri = rrs[i0 + ar];
    const int awbyte = ar * 128 + ((ac * 2) ^ ((ar & 7) << 4));
    const int NT = (TWON / KSLICE) / 64;   // 32
    f32x4 acc[4][4] = {};
    float4 v0, v1, c0, c1, s0, s1;
    auto LOADA = [&](int it) {
        const float* lp = L + (size_t)(i0 + ar) * TWON + kbase + it * 64 + ac;
        v0 = *reinterpret_cast<const float4*>(lp);
        v1 = *reinterpret_cast<const float4*>(lp + 4);
        c0 = *reinterpret_cast<const float4*>(cm + kbase + it * 64 + ac);
        c1 = *reinterpret_cast<const float4*>(cm + kbase + it * 64 + ac + 4);
        s0 = *reinterpret_cast<const float4*>(rcs + kbase + it * 64 + ac);
        s1 = *reinterpret_cast<const float4*>(rcs + kbase + it * 64 + ac + 4);
    };
    auto WRITEA = [&](int buf) {
        short8 av;
        av[0] = (short)f2bf(__expf(v0.x - hrm - 0.5f * c0.x) * sri * s0.x);
        av[1] = (short)f2bf(__expf(v0.y - hrm - 0.5f * c0.y) * sri * s0.y);
        av[2] = (short)f2bf(__expf(v0.z - hrm - 0.5f * c0.z) * sri * s0.z);
        av[3] = (short)f2bf(__expf(v0.w - hrm - 0.5f * c0.w) * sri * s0.w);
        av[4] = (short)f2bf(__expf(v1.x - hrm - 0.5f * c1.x) * sri * s1.x);
        av[5] = (short)f2bf(__expf(v1.y - hrm - 0.5f * c1.y) * sri * s1.y);
        av[6] = (short)f2bf(__expf(v1.z - hrm - 0.5f * c1.z) * sri * s1.z);
        av[7] = (short)f2bf(__expf(v1.w - hrm - 0.5f * c1.w) * sri * s1.w);
        *reinterpret_cast<short8*>(lds + buf * 8192 + awbyte) = av;
    };
    LOADA(0);
    WRITEA(0);
    __syncthreads();
    int cur = 0;
    for (int it = 0; it < NT; ++it) {
        if (it + 1 < NT) LOADA(it + 1);      // prefetch next A rows (T14)
        #pragma unroll
        for (int kk = 0; kk < 2; ++kk) {
            short8 af[4], bfr[4];
            #pragma unroll
            for (int m = 0; m < 4; ++m) {
                const int row = m * 16 + (lane & 15);
                const int off = cur * 8192 + row * 128 +
                                ((kk * 64 + (lane >> 4) * 16) ^ ((row & 7) << 4));
                af[m] = *reinterpret_cast<const short8*>(lds + off);
            }
            #pragma unroll
            for (int n = 0; n < 4; ++n) {
                const int d = wn + n * 16 + (lane & 15);
                bfr[n] = *reinterpret_cast<const short8*>(
                    b2t + (size_t)d * TWON + kbase + it * 64 + kk * 32 + (lane >> 4) * 8);
            }
            #pragma unroll
            for (int m = 0; m < 4; ++m)
                #pragma unroll
                for (int n = 0; n < 4; ++n)
                    acc[m][n] = mfma16(af[m], bfr[n], acc[m][n]);
        }
        if (it + 1 < NT) WRITEA(cur ^ 1);
        __syncthreads();
        cur ^= 1;
    }
    float* pout = part + (size_t)blockIdx.y * NN * DD;
    #pragma unroll
    for (int m = 0; m < 4; ++m)
        #pragma unroll
        for (int n = 0; n < 4; ++n) {
            const int d = wn + n * 16 + (lane & 15);
            #pragma unroll
            for (int r4 = 0; r4 < 4; ++r4) {
                const int i = i0 + m * 16 + (lane >> 4) * 4 + r4;
                pout[(size_t)i * DD + d] = acc[m][n][r4];
            }
        }
}

// ---------------- reduce partials
__global__ __launch_bounds__(256)
void reduce_k(const float* __restrict__ part, float* __restrict__ out) {
    const size_t e4 = ((size_t)blockIdx.x * 256 + threadIdx.x) * 4;
    float4 a = *reinterpret_cast<const float4*>(part + e4);
    #pragma unroll
    for (int s = 1; s < KSLICE; ++s) {
        float4 b = *reinterpret_cast<const float4*>(part + (size_t)s * NN * DD + e4);
        a.x += b.x; a.y += b.y; a.z += b.z; a.w += b.w;
    }
    *reinterpret_cast<float4*>(out + e4) = a;
}

extern "C" void kernel_launch(void* const* d_in, const int* in_sizes, int n_in,
                              void* d_out, int out_size, void* d_ws, size_t ws_size,
                              hipStream_t stream) {
    const float* x = (const float*)d_in[0];
    const float* y = (const float*)d_in[1];
    float* out = (float*)d_out;

    char* w = (char*)d_ws;
    const size_t OFF_BHI  = 134217728;                 // L ends at 128Mi
    const size_t OFF_BLO  = OFF_BHI + (1u << 23);      // 136Mi
    const size_t OFF_RPM  = OFF_BLO + (1u << 23);      // 144Mi (gemm1-time)
    const size_t OFF_RPS  = OFF_RPM + (1u << 20);
    const size_t OFF_CPM  = OFF_RPS + (1u << 20);
    const size_t OFF_CPS  = OFF_CPM + (1u << 20);
    const size_t OFF_PART = OFF_BLO;                   // 136Mi..168Mi (gemm2-time, overlaps blo+partial-stats)
    const size_t OFF_TAIL = OFF_BLO + (1u << 25);      // 168Mi

    float* L    = (float*)w;
    u16*   bhi  = (u16*)(w + OFF_BHI);
    u16*   blo  = (u16*)(w + OFF_BLO);
    u16*   b2t  = bhi;                                 // reuse bhi region after gemm1
    float* rpm  = (float*)(w + OFF_RPM);
    float* rps  = (float*)(w + OFF_RPS);
    float* cpm  = (float*)(w + OFF_CPM);
    float* cps  = (float*)(w + OFF_CPS);
    float* part = (float*)(w + OFF_PART);
    float* nb   = (float*)(w + OFF_TAIL);              // 8192
    float* rm   = nb  + TWON;                          // 4096
    float* rrs  = rm  + NN;                            // 4096
    float* cm   = rrs + NN;                            // 8192
    float* rcs  = cm  + TWON;                          // 8192

    prep_k<<<TWON, 64, 0, stream>>>(x, y, bhi, blo, nb);
    gemm1_k<<<dim3(TWON / 128, NN / 128), 256, 0, stream>>>(bhi, blo, nb, L,
                                                            rpm, rps, cpm, cps);
    row_comb_k<<<NN / 256, 256, 0, stream>>>(rpm, rps, rm, rrs);
    col_comb_k<<<TWON / 256, 256, 0, stream>>>(cpm, cps, cm, rcs);
    b2t_k<<<dim3(TWON / 32, DD / 32), dim3(32, 8), 0, stream>>>(x, y, b2t);
    gemm2_k<<<dim3(NN / 64, KSLICE), 512, 0, stream>>>(L, b2t, rm, rrs, cm, rcs, part);
    reduce_k<<<(NN * DD / 4) / 256, 256, 0, stream>>>(part, out);
}

// Round 6
// 243.963 us; speedup vs baseline: 1.3265x; 1.3265x over previous
//
#include <hip/hip_runtime.h>
#include <math.h>

#define NN   4096
#define DD   512
#define TWON 8192
#define KSLICE 4

typedef _Float16 half_t;
using half8 = __attribute__((ext_vector_type(8))) half_t;
using f32x4 = __attribute__((ext_vector_type(4))) float;

__device__ __forceinline__ void gl16(const void* g, void* l) {
    __builtin_amdgcn_global_load_lds(
        (const __attribute__((address_space(1))) void*)g,
        (__attribute__((address_space(3))) void*)l, 16, 0, 0);
}
__device__ __forceinline__ f32x4 mfma16h(half8 a, half8 b, f32x4 c) {
    return __builtin_amdgcn_mfma_f32_16x16x32_f16(a, b, c, 0, 0, 0);
}

// ---------------- prep: b=[y;x] -> f16 hi/lo split + norms nb[8192]
__global__ __launch_bounds__(64)
void prep_k(const float* __restrict__ x, const float* __restrict__ y,
            half_t* __restrict__ bhi, half_t* __restrict__ blo, float* __restrict__ nb) {
    int r = blockIdx.x;           // 0..8191
    int l = threadIdx.x;          // 64
    const float* src = (r < NN) ? (y + (size_t)r * DD) : (x + (size_t)(r - NN) * DD);
    float4 v0 = *reinterpret_cast<const float4*>(src + l * 8);
    float4 v1 = *reinterpret_cast<const float4*>(src + l * 8 + 4);
    float e[8] = {v0.x, v0.y, v0.z, v0.w, v1.x, v1.y, v1.z, v1.w};
    float s = 0.f;
    half8 h, lo;
    #pragma unroll
    for (int q = 0; q < 8; ++q) {
        s += e[q] * e[q];
        half_t hq = (half_t)e[q];
        h[q]  = hq;
        lo[q] = (half_t)(e[q] - (float)hq);
    }
    *reinterpret_cast<half8*>(bhi + (size_t)r * DD + l * 8) = h;
    *reinterpret_cast<half8*>(blo + (size_t)r * DD + l * 8) = lo;
    #pragma unroll
    for (int off = 32; off; off >>= 1) s += __shfl_down(s, off);
    if (l == 0) nb[r] = s;
}

// ---------------- b2t: b2t[d][k] = k<N ? y[k][d] : -x[k-N][d]  (f16, 512x8192)
// Reads ORIGINAL f32 inputs — b2t aliases bhi region (round-3 lesson).
__global__ __launch_bounds__(256)
void b2t_k(const float* __restrict__ x, const float* __restrict__ y, half_t* __restrict__ b2t) {
    __shared__ float tl[32][33];
    int k0 = blockIdx.x * 32, d0 = blockIdx.y * 32;
    int tx = threadIdx.x, ty = threadIdx.y;   // (32,8)
    const float* src = (k0 < NN) ? y : x;
    int row0 = (k0 < NN) ? k0 : (k0 - NN);
    #pragma unroll
    for (int j = 0; j < 4; ++j)
        tl[ty + 8 * j][tx] = src[(size_t)(row0 + ty + 8 * j) * DD + d0 + tx];
    __syncthreads();
    float sgn = (k0 < NN) ? 1.f : -1.f;
    #pragma unroll
    for (int j = 0; j < 4; ++j) {
        float v = tl[tx][ty + 8 * j] * sgn;
        b2t[(size_t)(d0 + ty + 8 * j) * TWON + k0 + tx] = (half_t)v;
    }
}

// ---------------- GEMM1: f16 2-term split MFMA + logits + fused partial stats
// 256 threads / 4 waves — round-4-proven skeleton, f16 2-term split.
__global__ __launch_bounds__(256)
void gemm1_k(const half_t* __restrict__ bhi, const half_t* __restrict__ blo,
             const float* __restrict__ nb, float* __restrict__ L,
             float* __restrict__ rpm, float* __restrict__ rps,
             float* __restrict__ cpm, float* __restrict__ cps) {
    __shared__ unsigned char lds[49152]; // Ahi@0 Alo@16K Bhi@32K, each 128x64 f16 swizzled
    const int t = threadIdx.x;
    const int wave = t >> 6, lane = t & 63;
    const int i0 = blockIdx.y * 128, j0 = blockIdx.x * 128;
    const int wm = (wave >> 1) * 64, wn = (wave & 1) * 64;
    const half_t* ahig = bhi + (size_t)NN * DD;  // x rows are b rows 4096..8191
    const half_t* alog = blo + (size_t)NN * DD;
    f32x4 acc[4][4] = {};
    for (int k0 = 0; k0 < DD; k0 += 64) {
        __syncthreads();
        #pragma unroll
        for (int q = 0; q < 4; ++q) {
            const int dbase = (wave * 4 + q) * 1024;
            const int p  = dbase + lane * 16;
            const int r  = p >> 7;
            const int cb = (p & 127) ^ ((r & 7) << 4);
            const size_t offA = (size_t)(i0 + r) * DD + k0 + (cb >> 1);
            const size_t offB = (size_t)(j0 + r) * DD + k0 + (cb >> 1);
            gl16(ahig + offA, lds + dbase);
            gl16(alog + offA, lds + 16384 + dbase);
            gl16(bhi  + offB, lds + 32768 + dbase);
        }
        asm volatile("s_waitcnt vmcnt(0)" ::: "memory");
        __builtin_amdgcn_sched_barrier(0);
        __syncthreads();
        #pragma unroll
        for (int kk = 0; kk < 2; ++kk) {
            half8 ah[4], al[4];
            #pragma unroll
            for (int m = 0; m < 4; ++m) {
                const int row = wm + m * 16 + (lane & 15);
                const int off = row * 128 + ((kk * 64 + (lane >> 4) * 16) ^ ((row & 7) << 4));
                ah[m] = *reinterpret_cast<const half8*>(lds + off);
                al[m] = *reinterpret_cast<const half8*>(lds + 16384 + off);
            }
            #pragma unroll
            for (int n = 0; n < 4; ++n) {
                const int row = wn + n * 16 + (lane & 15);
                const int off = row * 128 + ((kk * 64 + (lane >> 4) * 16) ^ ((row & 7) << 4));
                half8 bh = *reinterpret_cast<const half8*>(lds + 32768 + off);
                #pragma unroll
                for (int m = 0; m < 4; ++m) {
                    acc[m][n] = mfma16h(ah[m], bh, acc[m][n]);
                    acc[m][n] = mfma16h(al[m], bh, acc[m][n]);
                }
            }
        }
    }
    // ---- transform acc -> logits, store L
    float nbj[4];
    #pragma unroll
    for (int n = 0; n < 4; ++n) nbj[n] = nb[j0 + wn + n * 16 + (lane & 15)];
    #pragma unroll
    for (int m = 0; m < 4; ++m) {
        #pragma unroll
        for (int r4 = 0; r4 < 4; ++r4) {
            const int i = i0 + wm + m * 16 + (lane >> 4) * 4 + r4;
            const float nxi = nb[NN + i];
            #pragma unroll
            for (int n = 0; n < 4; ++n) {
                const int j = j0 + wn + n * 16 + (lane & 15);
                float sq = nxi + nbj[n] - 2.0f * acc[m][n][r4];
                float lg = -10.0f * sqrtf(fmaxf(sq, 1e-12f));
                if (j == i + NN) lg = -1e7f;
                acc[m][n][r4] = lg;
                L[(size_t)i * TWON + j] = lg;
            }
        }
    }
    // ---- per-tile row partials (max+sum over this block's 128 cols)
    float rmx[16], rsm[16];
    #pragma unroll
    for (int m = 0; m < 4; ++m)
        #pragma unroll
        for (int r4 = 0; r4 < 4; ++r4) {
            const int idx = m * 4 + r4;
            float M = fmaxf(fmaxf(acc[m][0][r4], acc[m][1][r4]),
                            fmaxf(acc[m][2][r4], acc[m][3][r4]));
            float S = __expf(acc[m][0][r4] - M) + __expf(acc[m][1][r4] - M) +
                      __expf(acc[m][2][r4] - M) + __expf(acc[m][3][r4] - M);
            rmx[idx] = M; rsm[idx] = S;
        }
    #pragma unroll
    for (int off = 1; off < 16; off <<= 1) {
        #pragma unroll
        for (int idx = 0; idx < 16; ++idx) {
            float om = __shfl_xor(rmx[idx], off);
            float os = __shfl_xor(rsm[idx], off);
            float M = fmaxf(rmx[idx], om);
            rsm[idx] = rsm[idx] * __expf(rmx[idx] - M) + os * __expf(om - M);
            rmx[idx] = M;
        }
    }
    // ---- per-tile col partials (max+sum over this block's 128 rows)
    float cmx[4], csm[4];
    #pragma unroll
    for (int n = 0; n < 4; ++n) {
        float M = -3.0e38f;
        #pragma unroll
        for (int m = 0; m < 4; ++m)
            #pragma unroll
            for (int r4 = 0; r4 < 4; ++r4) M = fmaxf(M, acc[m][n][r4]);
        float S = 0.f;
        #pragma unroll
        for (int m = 0; m < 4; ++m)
            #pragma unroll
            for (int r4 = 0; r4 < 4; ++r4) S += __expf(acc[m][n][r4] - M);
        cmx[n] = M; csm[n] = S;
    }
    #pragma unroll
    for (int off = 16; off < 64; off <<= 1) {
        #pragma unroll
        for (int n = 0; n < 4; ++n) {
            float om = __shfl_xor(cmx[n], off);
            float os = __shfl_xor(csm[n], off);
            float M = fmaxf(cmx[n], om);
            csm[n] = csm[n] * __expf(cmx[n] - M) + os * __expf(om - M);
            cmx[n] = M;
        }
    }
    // ---- combine across waves via LDS, write per-tile partials
    __syncthreads();
    float* red = reinterpret_cast<float*>(lds);   // rows [0..512), cols [512..1024)
    if ((lane & 15) == 0) {
        #pragma unroll
        for (int m = 0; m < 4; ++m)
            #pragma unroll
            for (int r4 = 0; r4 < 4; ++r4) {
                const int r = wm + m * 16 + (lane >> 4) * 4 + r4;
                red[((wave & 1) * 128 + r) * 2]     = rmx[m * 4 + r4];
                red[((wave & 1) * 128 + r) * 2 + 1] = rsm[m * 4 + r4];
            }
    }
    if (lane < 16) {
        #pragma unroll
        for (int n = 0; n < 4; ++n) {
            const int c = wn + n * 16 + lane;
            red[512 + ((wave >> 1) * 128 + c) * 2]     = cmx[n];
            red[512 + ((wave >> 1) * 128 + c) * 2 + 1] = csm[n];
        }
    }
    __syncthreads();
    if (t < 128) {
        const int r = t;
        float m0 = red[r * 2], s0 = red[r * 2 + 1];
        float m1 = red[(128 + r) * 2], s1 = red[(128 + r) * 2 + 1];
        float M = fmaxf(m0, m1);
        float S = s0 * __expf(m0 - M) + s1 * __expf(m1 - M);
        rpm[(size_t)blockIdx.x * NN + i0 + r] = M;
        rps[(size_t)blockIdx.x * NN + i0 + r] = S;
    } else {
        const int c = t - 128;
        float m0 = red[512 + c * 2], s0 = red[512 + c * 2 + 1];
        float m1 = red[512 + (128 + c) * 2], s1 = red[512 + (128 + c) * 2 + 1];
        float M = fmaxf(m0, m1);
        float S = s0 * __expf(m0 - M) + s1 * __expf(m1 - M);
        cpm[(size_t)blockIdx.y * TWON + j0 + c] = M;
        cps[(size_t)blockIdx.y * TWON + j0 + c] = S;
    }
}

// ---------------- combine row partials (64 j-tiles) -> rm, rrs
__global__ __launch_bounds__(256)
void row_comb_k(const float* __restrict__ rpm, const float* __restrict__ rps,
                float* __restrict__ rm, float* __restrict__ rrs) {
    int i = blockIdx.x * 256 + threadIdx.x;
    float M = -3.0e38f;
    for (int tt = 0; tt < TWON / 128; ++tt) M = fmaxf(M, rpm[(size_t)tt * NN + i]);
    float S = 0.f;
    for (int tt = 0; tt < TWON / 128; ++tt)
        S += rps[(size_t)tt * NN + i] * __expf(rpm[(size_t)tt * NN + i] - M);
    rm[i] = M; rrs[i] = rsqrtf(S);
}

// ---------------- combine col partials (32 i-tiles) -> cm, rcs
__global__ __launch_bounds__(256)
void col_comb_k(const float* __restrict__ cpm, const float* __restrict__ cps,
                float* __restrict__ cm, float* __restrict__ rcs) {
    int j = blockIdx.x * 256 + threadIdx.x;
    float M = -3.0e38f;
    for (int tt = 0; tt < NN / 128; ++tt) M = fmaxf(M, cpm[(size_t)tt * TWON + j]);
    float S = 0.f;
    for (int tt = 0; tt < NN / 128; ++tt)
        S += cps[(size_t)tt * TWON + j] * __expf(cpm[(size_t)tt * TWON + j] - M);
    cm[j] = M; rcs[j] = rsqrtf(S);
}

// ---------------- GEMM2: split-K, A from L (fused softmax, reg-staged dbuf LDS),
// B frags straight from L2, partial outputs — round-4-proven structure.
__global__ __launch_bounds__(512)
void gemm2_k(const float* __restrict__ L, const half_t* __restrict__ b2t,
             const float* __restrict__ rm, const float* __restrict__ rrs,
             const float* __restrict__ cm, const float* __restrict__ rcs,
             float* __restrict__ part) {
    __shared__ unsigned char lds[16384];   // 2 x (64x64 f16 A tile, swizzled)
    const int t = threadIdx.x;
    const int wave = t >> 6, lane = t & 63;
    const int i0 = blockIdx.x * 64;
    const int kbase = blockIdx.y * (TWON / KSLICE);
    const int wn = wave * 64;
    const int ar = t >> 3;          // 0..63 staging row
    const int ac = (t & 7) * 8;     // staging col
    const float hrm = 0.5f * rm[i0 + ar];
    const float sri = rrs[i0 + ar];
    const int awbyte = ar * 128 + ((ac * 2) ^ ((ar & 7) << 4));
    const int NT = (TWON / KSLICE) / 64;   // 32
    f32x4 acc[4][4] = {};
    float4 v0, v1, c0, c1, s0, s1;
    auto LOADA = [&](int it) {
        const float* lp = L + (size_t)(i0 + ar) * TWON + kbase + it * 64 + ac;
        v0 = *reinterpret_cast<const float4*>(lp);
        v1 = *reinterpret_cast<const float4*>(lp + 4);
        c0 = *reinterpret_cast<const float4*>(cm + kbase + it * 64 + ac);
        c1 = *reinterpret_cast<const float4*>(cm + kbase + it * 64 + ac + 4);
        s0 = *reinterpret_cast<const float4*>(rcs + kbase + it * 64 + ac);
        s1 = *reinterpret_cast<const float4*>(rcs + kbase + it * 64 + ac + 4);
    };
    auto WRITEA = [&](int buf) {
        half8 av;
        av[0] = (half_t)(__expf(v0.x - hrm - 0.5f * c0.x) * sri * s0.x);
        av[1] = (half_t)(__expf(v0.y - hrm - 0.5f * c0.y) * sri * s0.y);
        av[2] = (half_t)(__expf(v0.z - hrm - 0.5f * c0.z) * sri * s0.z);
        av[3] = (half_t)(__expf(v0.w - hrm - 0.5f * c0.w) * sri * s0.w);
        av[4] = (half_t)(__expf(v1.x - hrm - 0.5f * c1.x) * sri * s1.x);
        av[5] = (half_t)(__expf(v1.y - hrm - 0.5f * c1.y) * sri * s1.y);
        av[6] = (half_t)(__expf(v1.z - hrm - 0.5f * c1.z) * sri * s1.z);
        av[7] = (half_t)(__expf(v1.w - hrm - 0.5f * c1.w) * sri * s1.w);
        *reinterpret_cast<half8*>(lds + buf * 8192 + awbyte) = av;
    };
    LOADA(0);
    WRITEA(0);
    __syncthreads();
    int cur = 0;
    for (int it = 0; it < NT; ++it) {
        if (it + 1 < NT) LOADA(it + 1);      // prefetch next A rows (T14)
        #pragma unroll
        for (int kk = 0; kk < 2; ++kk) {
            half8 af[4], bfr[4];
            #pragma unroll
            for (int m = 0; m < 4; ++m) {
                const int row = m * 16 + (lane & 15);
                const int off = cur * 8192 + row * 128 +
                                ((kk * 64 + (lane >> 4) * 16) ^ ((row & 7) << 4));
                af[m] = *reinterpret_cast<const half8*>(lds + off);
            }
            #pragma unroll
            for (int n = 0; n < 4; ++n) {
                const int d = wn + n * 16 + (lane & 15);
                bfr[n] = *reinterpret_cast<const half8*>(
                    b2t + (size_t)d * TWON + kbase + it * 64 + kk * 32 + (lane >> 4) * 8);
            }
            #pragma unroll
            for (int m = 0; m < 4; ++m)
                #pragma unroll
                for (int n = 0; n < 4; ++n)
                    acc[m][n] = mfma16h(af[m], bfr[n], acc[m][n]);
        }
        if (it + 1 < NT) WRITEA(cur ^ 1);
        __syncthreads();
        cur ^= 1;
    }
    float* pout = part + (size_t)blockIdx.y * NN * DD;
    #pragma unroll
    for (int m = 0; m < 4; ++m)
        #pragma unroll
        for (int n = 0; n < 4; ++n) {
            const int d = wn + n * 16 + (lane & 15);
            #pragma unroll
            for (int r4 = 0; r4 < 4; ++r4) {
                const int i = i0 + m * 16 + (lane >> 4) * 4 + r4;
                pout[(size_t)i * DD + d] = acc[m][n][r4];
            }
        }
}

// ---------------- reduce partials
__global__ __launch_bounds__(256)
void reduce_k(const float* __restrict__ part, float* __restrict__ out) {
    const size_t e4 = ((size_t)blockIdx.x * 256 + threadIdx.x) * 4;
    float4 a = *reinterpret_cast<const float4*>(part + e4);
    #pragma unroll
    for (int s = 1; s < KSLICE; ++s) {
        float4 b = *reinterpret_cast<const float4*>(part + (size_t)s * NN * DD + e4);
        a.x += b.x; a.y += b.y; a.z += b.z; a.w += b.w;
    }
    *reinterpret_cast<float4*>(out + e4) = a;
}

extern "C" void kernel_launch(void* const* d_in, const int* in_sizes, int n_in,
                              void* d_out, int out_size, void* d_ws, size_t ws_size,
                              hipStream_t stream) {
    const float* x = (const float*)d_in[0];
    const float* y = (const float*)d_in[1];
    float* out = (float*)d_out;

    char* w = (char*)d_ws;
    const size_t OFF_BHI  = 134217728;                 // L ends at 128Mi
    const size_t OFF_BLO  = OFF_BHI + (1u << 23);      // 136Mi
    const size_t OFF_RPM  = OFF_BLO + (1u << 23);      // 144Mi (gemm1-time)
    const size_t OFF_RPS  = OFF_RPM + (1u << 20);
    const size_t OFF_CPM  = OFF_RPS + (1u << 20);
    const size_t OFF_CPS  = OFF_CPM + (1u << 20);
    const size_t OFF_PART = OFF_BLO;                   // 136Mi..168Mi (gemm2-time)
    const size_t OFF_TAIL = OFF_BLO + (1u << 25);      // 168Mi

    float*  L    = (float*)w;
    half_t* bhi  = (half_t*)(w + OFF_BHI);
    half_t* blo  = (half_t*)(w + OFF_BLO);
    half_t* b2t  = bhi;                                // reuse bhi region after gemm1
    float*  rpm  = (float*)(w + OFF_RPM);
    float*  rps  = (float*)(w + OFF_RPS);
    float*  cpm  = (float*)(w + OFF_CPM);
    float*  cps  = (float*)(w + OFF_CPS);
    float*  part = (float*)(w + OFF_PART);
    float*  nb   = (float*)(w + OFF_TAIL);             // 8192
    float*  rm   = nb  + TWON;                         // 4096
    float*  rrs  = rm  + NN;                           // 4096
    float*  cm   = rrs + NN;                           // 8192
    float*  rcs  = cm  + TWON;                         // 8192

    prep_k<<<TWON, 64, 0, stream>>>(x, y, bhi, blo, nb);
    gemm1_k<<<dim3(TWON / 128, NN / 128), 256, 0, stream>>>(bhi, blo, nb, L,
                                                            rpm, rps, cpm, cps);
    row_comb_k<<<NN / 256, 256, 0, stream>>>(rpm, rps, rm, rrs);
    col_comb_k<<<TWON / 256, 256, 0, stream>>>(cpm, cps, cm, rcs);
    b2t_k<<<dim3(TWON / 32, DD / 32), dim3(32, 8), 0, stream>>>(x, y, b2t);
    gemm2_k<<<dim3(NN / 64, KSLICE), 512, 0, stream>>>(L, b2t, rm, rrs, cm, rcs, part);
    reduce_k<<<(NN * DD / 4) / 256, 256, 0, stream>>>(part, out);
}

// Round 7
// 228.372 us; speedup vs baseline: 1.4170x; 1.0683x over previous
//
#include <hip/hip_runtime.h>
#include <math.h>

#define NN   4096
#define DD   512
#define TWON 8192
#define KSLICE 4

typedef _Float16 half_t;
using half8 = __attribute__((ext_vector_type(8))) half_t;
using f32x4 = __attribute__((ext_vector_type(4))) float;

__device__ __forceinline__ void gl16(const void* g, void* l) {
    __builtin_amdgcn_global_load_lds(
        (const __attribute__((address_space(1))) void*)g,
        (__attribute__((address_space(3))) void*)l, 16, 0, 0);
}
__device__ __forceinline__ f32x4 mfma16h(half8 a, half8 b, f32x4 c) {
    return __builtin_amdgcn_mfma_f32_16x16x32_f16(a, b, c, 0, 0, 0);
}

// ---------------- prep: b=[y;x] -> f16 hi/lo split + norms nb[8192]
__global__ __launch_bounds__(64)
void prep_k(const float* __restrict__ x, const float* __restrict__ y,
            half_t* __restrict__ bhi, half_t* __restrict__ blo, float* __restrict__ nb) {
    int r = blockIdx.x;           // 0..8191
    int l = threadIdx.x;          // 64
    const float* src = (r < NN) ? (y + (size_t)r * DD) : (x + (size_t)(r - NN) * DD);
    float4 v0 = *reinterpret_cast<const float4*>(src + l * 8);
    float4 v1 = *reinterpret_cast<const float4*>(src + l * 8 + 4);
    float e[8] = {v0.x, v0.y, v0.z, v0.w, v1.x, v1.y, v1.z, v1.w};
    float s = 0.f;
    half8 h, lo;
    #pragma unroll
    for (int q = 0; q < 8; ++q) {
        s += e[q] * e[q];
        half_t hq = (half_t)e[q];
        h[q]  = hq;
        lo[q] = (half_t)(e[q] - (float)hq);
    }
    *reinterpret_cast<half8*>(bhi + (size_t)r * DD + l * 8) = h;
    *reinterpret_cast<half8*>(blo + (size_t)r * DD + l * 8) = lo;
    #pragma unroll
    for (int off = 32; off; off >>= 1) s += __shfl_down(s, off);
    if (l == 0) nb[r] = s;
}

// ---------------- b2t: b2t[d][k] = k<N ? y[k][d] : -x[k-N][d]  (f16, 512x8192)
// Reads ORIGINAL f32 inputs — b2t aliases bhi region (round-3 lesson).
__global__ __launch_bounds__(256)
void b2t_k(const float* __restrict__ x, const float* __restrict__ y, half_t* __restrict__ b2t) {
    __shared__ float tl[32][33];
    int k0 = blockIdx.x * 32, d0 = blockIdx.y * 32;
    int tx = threadIdx.x, ty = threadIdx.y;   // (32,8)
    const float* src = (k0 < NN) ? y : x;
    int row0 = (k0 < NN) ? k0 : (k0 - NN);
    #pragma unroll
    for (int j = 0; j < 4; ++j)
        tl[ty + 8 * j][tx] = src[(size_t)(row0 + ty + 8 * j) * DD + d0 + tx];
    __syncthreads();
    float sgn = (k0 < NN) ? 1.f : -1.f;
    #pragma unroll
    for (int j = 0; j < 4; ++j) {
        float v = tl[tx][ty + 8 * j] * sgn;
        b2t[(size_t)(d0 + ty + 8 * j) * TWON + k0 + tx] = (half_t)v;
    }
}

// ---------------- GEMM1: f16 2-term split MFMA + logits + fused partial stats
// 256 threads / 4 waves. Epilogue v2: shared-C single-exp partial sums.
__global__ __launch_bounds__(256)
void gemm1_k(const half_t* __restrict__ bhi, const half_t* __restrict__ blo,
             const float* __restrict__ nb, float* __restrict__ L,
             float* __restrict__ rpm, float* __restrict__ rps,
             float* __restrict__ cpm, float* __restrict__ cps) {
    __shared__ unsigned char lds[49152]; // Ahi@0 Alo@16K Bhi@32K, each 128x64 f16 swizzled
    const int t = threadIdx.x;
    const int wave = t >> 6, lane = t & 63;
    const int i0 = blockIdx.y * 128, j0 = blockIdx.x * 128;
    const int wm = (wave >> 1) * 64, wn = (wave & 1) * 64;
    const half_t* ahig = bhi + (size_t)NN * DD;  // x rows are b rows 4096..8191
    const half_t* alog = blo + (size_t)NN * DD;
    f32x4 acc[4][4] = {};
    for (int k0 = 0; k0 < DD; k0 += 64) {
        __syncthreads();
        #pragma unroll
        for (int q = 0; q < 4; ++q) {
            const int dbase = (wave * 4 + q) * 1024;
            const int p  = dbase + lane * 16;
            const int r  = p >> 7;
            const int cb = (p & 127) ^ ((r & 7) << 4);
            const size_t offA = (size_t)(i0 + r) * DD + k0 + (cb >> 1);
            const size_t offB = (size_t)(j0 + r) * DD + k0 + (cb >> 1);
            gl16(ahig + offA, lds + dbase);
            gl16(alog + offA, lds + 16384 + dbase);
            gl16(bhi  + offB, lds + 32768 + dbase);
        }
        asm volatile("s_waitcnt vmcnt(0)" ::: "memory");
        __builtin_amdgcn_sched_barrier(0);
        __syncthreads();
        #pragma unroll
        for (int kk = 0; kk < 2; ++kk) {
            half8 ah[4], al[4];
            #pragma unroll
            for (int m = 0; m < 4; ++m) {
                const int row = wm + m * 16 + (lane & 15);
                const int off = row * 128 + ((kk * 64 + (lane >> 4) * 16) ^ ((row & 7) << 4));
                ah[m] = *reinterpret_cast<const half8*>(lds + off);
                al[m] = *reinterpret_cast<const half8*>(lds + 16384 + off);
            }
            #pragma unroll
            for (int n = 0; n < 4; ++n) {
                const int row = wn + n * 16 + (lane & 15);
                const int off = row * 128 + ((kk * 64 + (lane >> 4) * 16) ^ ((row & 7) << 4));
                half8 bh = *reinterpret_cast<const half8*>(lds + 32768 + off);
                #pragma unroll
                for (int m = 0; m < 4; ++m) {
                    acc[m][n] = mfma16h(ah[m], bh, acc[m][n]);
                    acc[m][n] = mfma16h(al[m], bh, acc[m][n]);
                }
            }
        }
    }
    // ---- pass 1: acc -> logits, store L, track thread max
    float nbj[4];
    #pragma unroll
    for (int n = 0; n < 4; ++n) nbj[n] = nb[j0 + wn + n * 16 + (lane & 15)];
    float tmax = -3.0e38f;
    #pragma unroll
    for (int m = 0; m < 4; ++m) {
        #pragma unroll
        for (int r4 = 0; r4 < 4; ++r4) {
            const int i = i0 + wm + m * 16 + (lane >> 4) * 4 + r4;
            const float nxi = nb[NN + i];
            #pragma unroll
            for (int n = 0; n < 4; ++n) {
                const int j = j0 + wn + n * 16 + (lane & 15);
                float sq = nxi + nbj[n] - 2.0f * acc[m][n][r4];
                float lg = -10.0f * sqrtf(fmaxf(sq, 1e-12f));
                if (j == i + NN) lg = -1e7f;
                acc[m][n][r4] = lg;
                tmax = fmaxf(tmax, lg);
                L[(size_t)i * TWON + j] = lg;
            }
        }
    }
    // ---- block-wide shared max C (reference for ALL partials of this tile)
    #pragma unroll
    for (int off = 1; off < 64; off <<= 1) tmax = fmaxf(tmax, __shfl_xor(tmax, off));
    __syncthreads();                        // all waves done with K-loop LDS reads
    float* red = reinterpret_cast<float*>(lds);
    if (lane == 0) red[wave] = tmax;
    __syncthreads();
    const float C = fmaxf(fmaxf(red[0], red[1]), fmaxf(red[2], red[3]));
    __syncthreads();                        // everyone has C before red is reused
    // ---- pass 2: single exp per element; row/col partial sums (pure adds)
    float rs[16] = {}, cs[4] = {};
    #pragma unroll
    for (int m = 0; m < 4; ++m)
        #pragma unroll
        for (int r4 = 0; r4 < 4; ++r4) {
            const int idx = m * 4 + r4;
            #pragma unroll
            for (int n = 0; n < 4; ++n) {
                float e = __expf(acc[m][n][r4] - C);
                rs[idx] += e;
                cs[n]   += e;
            }
        }
    #pragma unroll
    for (int off = 1; off < 16; off <<= 1) {
        #pragma unroll
        for (int idx = 0; idx < 16; ++idx) rs[idx] += __shfl_xor(rs[idx], off);
    }
    #pragma unroll
    for (int off = 16; off < 64; off <<= 1) {
        #pragma unroll
        for (int n = 0; n < 4; ++n) cs[n] += __shfl_xor(cs[n], off);
    }
    // ---- cross-wave combine: rows in red[0..255], cols in red[256..511]
    if ((lane & 15) == 0) {
        #pragma unroll
        for (int m = 0; m < 4; ++m)
            #pragma unroll
            for (int r4 = 0; r4 < 4; ++r4) {
                const int r = wm + m * 16 + (lane >> 4) * 4 + r4;
                red[(wave & 1) * 128 + r] = rs[m * 4 + r4];
            }
    }
    if (lane < 16) {
        #pragma unroll
        for (int n = 0; n < 4; ++n) {
            const int c = wn + n * 16 + lane;
            red[256 + (wave >> 1) * 128 + c] = cs[n];
        }
    }
    __syncthreads();
    if (t < 128) {
        float S = red[t] + red[128 + t];
        rpm[(size_t)blockIdx.x * NN + i0 + t] = C;
        rps[(size_t)blockIdx.x * NN + i0 + t] = S;
    } else {
        const int c = t - 128;
        float S = red[256 + c] + red[384 + c];
        cpm[(size_t)blockIdx.y * TWON + j0 + c] = C;
        cps[(size_t)blockIdx.y * TWON + j0 + c] = S;
    }
}

// ---------------- combine row partials (64 j-tiles) -> rm, rrs
__global__ __launch_bounds__(256)
void row_comb_k(const float* __restrict__ rpm, const float* __restrict__ rps,
                float* __restrict__ rm, float* __restrict__ rrs) {
    int i = blockIdx.x * 256 + threadIdx.x;
    float M = -3.0e38f;
    for (int tt = 0; tt < TWON / 128; ++tt) M = fmaxf(M, rpm[(size_t)tt * NN + i]);
    float S = 0.f;
    for (int tt = 0; tt < TWON / 128; ++tt)
        S += rps[(size_t)tt * NN + i] * __expf(rpm[(size_t)tt * NN + i] - M);
    rm[i] = M; rrs[i] = rsqrtf(S);
}

// ---------------- combine col partials (32 i-tiles) -> cm, rcs
__global__ __launch_bounds__(256)
void col_comb_k(const float* __restrict__ cpm, const float* __restrict__ cps,
                float* __restrict__ cm, float* __restrict__ rcs) {
    int j = blockIdx.x * 256 + threadIdx.x;
    float M = -3.0e38f;
    for (int tt = 0; tt < NN / 128; ++tt) M = fmaxf(M, cpm[(size_t)tt * TWON + j]);
    float S = 0.f;
    for (int tt = 0; tt < NN / 128; ++tt)
        S += cps[(size_t)tt * TWON + j] * __expf(cpm[(size_t)tt * TWON + j] - M);
    cm[j] = M; rcs[j] = rsqrtf(S);
}

// ---------------- GEMM2: split-K, A from L (fused softmax, reg-staged dbuf LDS),
// B frags straight from L2, partial outputs. 1-D grid with XCD->kslice mapping
// so each XCD's L2 holds exactly ONE 2 MiB B slice (no cross-slice thrash).
__global__ __launch_bounds__(512)
void gemm2_k(const float* __restrict__ L, const half_t* __restrict__ b2t,
             const float* __restrict__ rm, const float* __restrict__ rrs,
             const float* __restrict__ cm, const float* __restrict__ rcs,
             float* __restrict__ part) {
    __shared__ unsigned char lds[16384];   // 2 x (64x64 f16 A tile, swizzled)
    const int t = threadIdx.x;
    const int wave = t >> 6, lane = t & 63;
    const int sw = blockIdx.x;             // 0..255
    const int xcd = sw & 7;
    const int kslice = xcd >> 1;           // 2 XCDs per kslice
    const int iblk = (sw >> 3) + (xcd & 1) * 32;
    const int i0 = iblk * 64;
    const int kbase = kslice * (TWON / KSLICE);
    const int wn = wave * 64;
    const int ar = t >> 3;          // 0..63 staging row
    const int ac = (t & 7) * 8;     // staging col
    const float hrm = 0.5f * rm[i0 + ar];
    const float sri = rrs[i0 + ar];
    const int awbyte = ar * 128 + ((ac * 2) ^ ((ar & 7) << 4));
    const int NT = (TWON / KSLICE) / 64;   // 32
    f32x4 acc[4][4] = {};
    float4 v0, v1, c0, c1, s0, s1;
    auto LOADA = [&](int it) {
        const float* lp = L + (size_t)(i0 + ar) * TWON + kbase + it * 64 + ac;
        v0 = *reinterpret_cast<const float4*>(lp);
        v1 = *reinterpret_cast<const float4*>(lp + 4);
        c0 = *reinterpret_cast<const float4*>(cm + kbase + it * 64 + ac);
        c1 = *reinterpret_cast<const float4*>(cm + kbase + it * 64 + ac + 4);
        s0 = *reinterpret_cast<const float4*>(rcs + kbase + it * 64 + ac);
        s1 = *reinterpret_cast<const float4*>(rcs + kbase + it * 64 + ac + 4);
    };
    auto WRITEA = [&](int buf) {
        half8 av;
        av[0] = (half_t)(__expf(v0.x - hrm - 0.5f * c0.x) * sri * s0.x);
        av[1] = (half_t)(__expf(v0.y - hrm - 0.5f * c0.y) * sri * s0.y);
        av[2] = (half_t)(__expf(v0.z - hrm - 0.5f * c0.z) * sri * s0.z);
        av[3] = (half_t)(__expf(v0.w - hrm - 0.5f * c0.w) * sri * s0.w);
        av[4] = (half_t)(__expf(v1.x - hrm - 0.5f * c1.x) * sri * s1.x);
        av[5] = (half_t)(__expf(v1.y - hrm - 0.5f * c1.y) * sri * s1.y);
        av[6] = (half_t)(__expf(v1.z - hrm - 0.5f * c1.z) * sri * s1.z);
        av[7] = (half_t)(__expf(v1.w - hrm - 0.5f * c1.w) * sri * s1.w);
        *reinterpret_cast<half8*>(lds + buf * 8192 + awbyte) = av;
    };
    LOADA(0);
    WRITEA(0);
    __syncthreads();
    int cur = 0;
    for (int it = 0; it < NT; ++it) {
        if (it + 1 < NT) LOADA(it + 1);      // prefetch next A rows (T14)
        #pragma unroll
        for (int kk = 0; kk < 2; ++kk) {
            half8 af[4], bfr[4];
            #pragma unroll
            for (int m = 0; m < 4; ++m) {
                const int row = m * 16 + (lane & 15);
                const int off = cur * 8192 + row * 128 +
                                ((kk * 64 + (lane >> 4) * 16) ^ ((row & 7) << 4));
                af[m] = *reinterpret_cast<const half8*>(lds + off);
            }
            #pragma unroll
            for (int n = 0; n < 4; ++n) {
                const int d = wn + n * 16 + (lane & 15);
                bfr[n] = *reinterpret_cast<const half8*>(
                    b2t + (size_t)d * TWON + kbase + it * 64 + kk * 32 + (lane >> 4) * 8);
            }
            #pragma unroll
            for (int m = 0; m < 4; ++m)
                #pragma unroll
                for (int n = 0; n < 4; ++n)
                    acc[m][n] = mfma16h(af[m], bfr[n], acc[m][n]);
        }
        if (it + 1 < NT) WRITEA(cur ^ 1);
        __syncthreads();
        cur ^= 1;
    }
    float* pout = part + (size_t)kslice * NN * DD;
    #pragma unroll
    for (int m = 0; m < 4; ++m)
        #pragma unroll
        for (int n = 0; n < 4; ++n) {
            const int d = wn + n * 16 + (lane & 15);
            #pragma unroll
            for (int r4 = 0; r4 < 4; ++r4) {
                const int i = i0 + m * 16 + (lane >> 4) * 4 + r4;
                pout[(size_t)i * DD + d] = acc[m][n][r4];
            }
        }
}

// ---------------- reduce partials
__global__ __launch_bounds__(256)
void reduce_k(const float* __restrict__ part, float* __restrict__ out) {
    const size_t e4 = ((size_t)blockIdx.x * 256 + threadIdx.x) * 4;
    float4 a = *reinterpret_cast<const float4*>(part + e4);
    #pragma unroll
    for (int s = 1; s < KSLICE; ++s) {
        float4 b = *reinterpret_cast<const float4*>(part + (size_t)s * NN * DD + e4);
        a.x += b.x; a.y += b.y; a.z += b.z; a.w += b.w;
    }
    *reinterpret_cast<float4*>(out + e4) = a;
}

extern "C" void kernel_launch(void* const* d_in, const int* in_sizes, int n_in,
                              void* d_out, int out_size, void* d_ws, size_t ws_size,
                              hipStream_t stream) {
    const float* x = (const float*)d_in[0];
    const float* y = (const float*)d_in[1];
    float* out = (float*)d_out;

    char* w = (char*)d_ws;
    const size_t OFF_BHI  = 134217728;                 // L ends at 128Mi
    const size_t OFF_BLO  = OFF_BHI + (1u << 23);      // 136Mi
    const size_t OFF_RPM  = OFF_BLO + (1u << 23);      // 144Mi (gemm1-time)
    const size_t OFF_RPS  = OFF_RPM + (1u << 20);
    const size_t OFF_CPM  = OFF_RPS + (1u << 20);
    const size_t OFF_CPS  = OFF_CPM + (1u << 20);
    const size_t OFF_PART = OFF_BLO;                   // 136Mi..168Mi (gemm2-time)
    const size_t OFF_TAIL = OFF_BLO + (1u << 25);      // 168Mi

    float*  L    = (float*)w;
    half_t* bhi  = (half_t*)(w + OFF_BHI);
    half_t* blo  = (half_t*)(w + OFF_BLO);
    half_t* b2t  = bhi;                                // reuse bhi region after gemm1
    float*  rpm  = (float*)(w + OFF_RPM);
    float*  rps  = (float*)(w + OFF_RPS);
    float*  cpm  = (float*)(w + OFF_CPM);
    float*  cps  = (float*)(w + OFF_CPS);
    float*  part = (float*)(w + OFF_PART);
    float*  nb   = (float*)(w + OFF_TAIL);             // 8192
    float*  rm   = nb  + TWON;                         // 4096
    float*  rrs  = rm  + NN;                           // 4096
    float*  cm   = rrs + NN;                           // 8192
    float*  rcs  = cm  + TWON;                         // 8192

    prep_k<<<TWON, 64, 0, stream>>>(x, y, bhi, blo, nb);
    gemm1_k<<<dim3(TWON / 128, NN / 128), 256, 0, stream>>>(bhi, blo, nb, L,
                                                            rpm, rps, cpm, cps);
    row_comb_k<<<NN / 256, 256, 0, stream>>>(rpm, rps, rm, rrs);
    col_comb_k<<<TWON / 256, 256, 0, stream>>>(cpm, cps, cm, rcs);
    b2t_k<<<dim3(TWON / 32, DD / 32), dim3(32, 8), 0, stream>>>(x, y, b2t);
    gemm2_k<<<256, 512, 0, stream>>>(L, b2t, rm, rrs, cm, rcs, part);
    reduce_k<<<(NN * DD / 4) / 256, 256, 0, stream>>>(part, out);
}

// Round 8
// 199.526 us; speedup vs baseline: 1.6219x; 1.1446x over previous
//
#include <hip/hip_runtime.h>
#include <math.h>

#define NN   4096
#define DD   512
#define TWON 8192
#define KSLICE 4

typedef _Float16 half_t;
using half8 = __attribute__((ext_vector_type(8))) half_t;
using f32x4 = __attribute__((ext_vector_type(4))) float;

__device__ __forceinline__ void gl16(const void* g, void* l) {
    __builtin_amdgcn_global_load_lds(
        (const __attribute__((address_space(1))) void*)g,
        (__attribute__((address_space(3))) void*)l, 16, 0, 0);
}
__device__ __forceinline__ f32x4 mfma16h(half8 a, half8 b, f32x4 c) {
    return __builtin_amdgcn_mfma_f32_16x16x32_f16(a, b, c, 0, 0, 0);
}

// ---------------- prep: b=[y;x] -> f16 + norms nb[8192]
__global__ __launch_bounds__(64)
void prep_k(const float* __restrict__ x, const float* __restrict__ y,
            half_t* __restrict__ bhi, float* __restrict__ nb) {
    int r = blockIdx.x;           // 0..8191
    int l = threadIdx.x;          // 64
    const float* src = (r < NN) ? (y + (size_t)r * DD) : (x + (size_t)(r - NN) * DD);
    float4 v0 = *reinterpret_cast<const float4*>(src + l * 8);
    float4 v1 = *reinterpret_cast<const float4*>(src + l * 8 + 4);
    float e[8] = {v0.x, v0.y, v0.z, v0.w, v1.x, v1.y, v1.z, v1.w};
    float s = 0.f;
    half8 h;
    #pragma unroll
    for (int q = 0; q < 8; ++q) {
        s += e[q] * e[q];
        h[q] = (half_t)e[q];
    }
    *reinterpret_cast<half8*>(bhi + (size_t)r * DD + l * 8) = h;
    #pragma unroll
    for (int off = 32; off; off >>= 1) s += __shfl_down(s, off);
    if (l == 0) nb[r] = s;
}

// ---------------- b2t: b2t[d][k] = k<N ? y[k][d] : -x[k-N][d]  (f16, 512x8192)
// Reads ORIGINAL f32 inputs — b2t aliases bhi region (round-3 lesson).
__global__ __launch_bounds__(256)
void b2t_k(const float* __restrict__ x, const float* __restrict__ y, half_t* __restrict__ b2t) {
    __shared__ float tl[32][33];
    int k0 = blockIdx.x * 32, d0 = blockIdx.y * 32;
    int tx = threadIdx.x, ty = threadIdx.y;   // (32,8)
    const float* src = (k0 < NN) ? y : x;
    int row0 = (k0 < NN) ? k0 : (k0 - NN);
    #pragma unroll
    for (int j = 0; j < 4; ++j)
        tl[ty + 8 * j][tx] = src[(size_t)(row0 + ty + 8 * j) * DD + d0 + tx];
    __syncthreads();
    float sgn = (k0 < NN) ? 1.f : -1.f;
    #pragma unroll
    for (int j = 0; j < 4; ++j) {
        float v = tl[tx][ty + 8 * j] * sgn;
        b2t[(size_t)(d0 + ty + 8 * j) * TWON + k0 + tx] = (half_t)v;
    }
}

// ---------------- GEMM1: single-term f16 MFMA + logits + fused partial stats
// 256 threads / 4 waves, m97-style 128x128 tile, BK=64.
__global__ __launch_bounds__(256)
void gemm1_k(const half_t* __restrict__ bhi,
             const float* __restrict__ nb, float* __restrict__ L,
             float* __restrict__ rpm, float* __restrict__ rps,
             float* __restrict__ cpm, float* __restrict__ cps) {
    __shared__ unsigned char lds[32768]; // Ahi@0 Bhi@16K, each 128x64 f16 swizzled
    const int t = threadIdx.x;
    const int wave = t >> 6, lane = t & 63;
    const int i0 = blockIdx.y * 128, j0 = blockIdx.x * 128;
    const int wm = (wave >> 1) * 64, wn = (wave & 1) * 64;
    const half_t* ahig = bhi + (size_t)NN * DD;  // x rows are b rows 4096..8191
    f32x4 acc[4][4] = {};
    for (int k0 = 0; k0 < DD; k0 += 64) {
        __syncthreads();
        #pragma unroll
        for (int q = 0; q < 4; ++q) {
            const int dbase = (wave * 4 + q) * 1024;
            const int p  = dbase + lane * 16;
            const int r  = p >> 7;
            const int cb = (p & 127) ^ ((r & 7) << 4);
            const size_t offA = (size_t)(i0 + r) * DD + k0 + (cb >> 1);
            const size_t offB = (size_t)(j0 + r) * DD + k0 + (cb >> 1);
            gl16(ahig + offA, lds + dbase);
            gl16(bhi  + offB, lds + 16384 + dbase);
        }
        asm volatile("s_waitcnt vmcnt(0)" ::: "memory");
        __builtin_amdgcn_sched_barrier(0);
        __syncthreads();
        #pragma unroll
        for (int kk = 0; kk < 2; ++kk) {
            half8 ah[4];
            #pragma unroll
            for (int m = 0; m < 4; ++m) {
                const int row = wm + m * 16 + (lane & 15);
                const int off = row * 128 + ((kk * 64 + (lane >> 4) * 16) ^ ((row & 7) << 4));
                ah[m] = *reinterpret_cast<const half8*>(lds + off);
            }
            #pragma unroll
            for (int n = 0; n < 4; ++n) {
                const int row = wn + n * 16 + (lane & 15);
                const int off = row * 128 + ((kk * 64 + (lane >> 4) * 16) ^ ((row & 7) << 4));
                half8 bh = *reinterpret_cast<const half8*>(lds + 16384 + off);
                #pragma unroll
                for (int m = 0; m < 4; ++m)
                    acc[m][n] = mfma16h(ah[m], bh, acc[m][n]);
            }
        }
    }
    // ---- pass 1: acc -> logits, store L, track thread max
    float nbj[4];
    #pragma unroll
    for (int n = 0; n < 4; ++n) nbj[n] = nb[j0 + wn + n * 16 + (lane & 15)];
    float tmax = -3.0e38f;
    #pragma unroll
    for (int m = 0; m < 4; ++m) {
        #pragma unroll
        for (int r4 = 0; r4 < 4; ++r4) {
            const int i = i0 + wm + m * 16 + (lane >> 4) * 4 + r4;
            const float nxi = nb[NN + i];
            #pragma unroll
            for (int n = 0; n < 4; ++n) {
                const int j = j0 + wn + n * 16 + (lane & 15);
                float sq = nxi + nbj[n] - 2.0f * acc[m][n][r4];
                float lg = -10.0f * sqrtf(fmaxf(sq, 1e-12f));
                if (j == i + NN) lg = -1e7f;
                acc[m][n][r4] = lg;
                tmax = fmaxf(tmax, lg);
                L[(size_t)i * TWON + j] = lg;
            }
        }
    }
    // ---- block-wide shared max C
    #pragma unroll
    for (int off = 1; off < 64; off <<= 1) tmax = fmaxf(tmax, __shfl_xor(tmax, off));
    __syncthreads();
    float* red = reinterpret_cast<float*>(lds);
    if (lane == 0) red[wave] = tmax;
    __syncthreads();
    const float C = fmaxf(fmaxf(red[0], red[1]), fmaxf(red[2], red[3]));
    __syncthreads();
    // ---- pass 2: single exp per element; row/col partial sums (pure adds)
    float rs[16] = {}, cs[4] = {};
    #pragma unroll
    for (int m = 0; m < 4; ++m)
        #pragma unroll
        for (int r4 = 0; r4 < 4; ++r4) {
            const int idx = m * 4 + r4;
            #pragma unroll
            for (int n = 0; n < 4; ++n) {
                float e = __expf(acc[m][n][r4] - C);
                rs[idx] += e;
                cs[n]   += e;
            }
        }
    #pragma unroll
    for (int off = 1; off < 16; off <<= 1) {
        #pragma unroll
        for (int idx = 0; idx < 16; ++idx) rs[idx] += __shfl_xor(rs[idx], off);
    }
    #pragma unroll
    for (int off = 16; off < 64; off <<= 1) {
        #pragma unroll
        for (int n = 0; n < 4; ++n) cs[n] += __shfl_xor(cs[n], off);
    }
    // ---- cross-wave combine: rows in red[0..255], cols in red[256..511]
    if ((lane & 15) == 0) {
        #pragma unroll
        for (int m = 0; m < 4; ++m)
            #pragma unroll
            for (int r4 = 0; r4 < 4; ++r4) {
                const int r = wm + m * 16 + (lane >> 4) * 4 + r4;
                red[(wave & 1) * 128 + r] = rs[m * 4 + r4];
            }
    }
    if (lane < 16) {
        #pragma unroll
        for (int n = 0; n < 4; ++n) {
            const int c = wn + n * 16 + lane;
            red[256 + (wave >> 1) * 128 + c] = cs[n];
        }
    }
    __syncthreads();
    if (t < 128) {
        float S = red[t] + red[128 + t];
        rpm[(size_t)blockIdx.x * NN + i0 + t] = C;
        rps[(size_t)blockIdx.x * NN + i0 + t] = S;
    } else {
        const int c = t - 128;
        float S = red[256 + c] + red[384 + c];
        cpm[(size_t)blockIdx.y * TWON + j0 + c] = C;
        cps[(size_t)blockIdx.y * TWON + j0 + c] = S;
    }
}

// ---------------- combine row partials (64 j-tiles) -> rm, rrs
__global__ __launch_bounds__(256)
void row_comb_k(const float* __restrict__ rpm, const float* __restrict__ rps,
                float* __restrict__ rm, float* __restrict__ rrs) {
    int i = blockIdx.x * 256 + threadIdx.x;
    float M = -3.0e38f;
    for (int tt = 0; tt < TWON / 128; ++tt) M = fmaxf(M, rpm[(size_t)tt * NN + i]);
    float S = 0.f;
    for (int tt = 0; tt < TWON / 128; ++tt)
        S += rps[(size_t)tt * NN + i] * __expf(rpm[(size_t)tt * NN + i] - M);
    rm[i] = M; rrs[i] = rsqrtf(S);
}

// ---------------- combine col partials (32 i-tiles) -> cm, rcs
__global__ __launch_bounds__(256)
void col_comb_k(const float* __restrict__ cpm, const float* __restrict__ cps,
                float* __restrict__ cm, float* __restrict__ rcs) {
    int j = blockIdx.x * 256 + threadIdx.x;
    float M = -3.0e38f;
    for (int tt = 0; tt < NN / 128; ++tt) M = fmaxf(M, cpm[(size_t)tt * TWON + j]);
    float S = 0.f;
    for (int tt = 0; tt < NN / 128; ++tt)
        S += cps[(size_t)tt * TWON + j] * __expf(cpm[(size_t)tt * TWON + j] - M);
    cm[j] = M; rcs[j] = rsqrtf(S);
}

// ---------------- GEMM2: split-K, A from L (fused softmax), depth-2 prefetch
// (two named register sets, loop unrolled x2 — rule #20), B frags from L2.
__global__ __launch_bounds__(512)
void gemm2_k(const float* __restrict__ L, const half_t* __restrict__ b2t,
             const float* __restrict__ rm, const float* __restrict__ rrs,
             const float* __restrict__ cm, const float* __restrict__ rcs,
             float* __restrict__ part) {
    __shared__ unsigned char lds[16384];   // 2 x (64x64 f16 A tile, swizzled)
    const int t = threadIdx.x;
    const int wave = t >> 6, lane = t & 63;
    const int sw = blockIdx.x;             // 0..255
    const int xcd = sw & 7;
    const int kslice = xcd >> 1;           // 2 XCDs per kslice
    const int iblk = (sw >> 3) + (xcd & 1) * 32;
    const int i0 = iblk * 64;
    const int kbase = kslice * (TWON / KSLICE);
    const int wn = wave * 64;
    const int ar = t >> 3;          // 0..63 staging row
    const int ac = (t & 7) * 8;     // staging col
    const float hrm = 0.5f * rm[i0 + ar];
    const float sri = rrs[i0 + ar];
    const int awbyte = ar * 128 + ((ac * 2) ^ ((ar & 7) << 4));
    const int NT = (TWON / KSLICE) / 64;   // 32, even
    f32x4 acc[4][4] = {};
    // two named prefetch sets (static indexing only)
    float4 a_v0, a_v1, a_c0, a_c1, a_s0, a_s1;
    float4 b_v0, b_v1, b_c0, b_c1, b_s0, b_s1;
    auto LOADA0 = [&](int it) {
        const float* lp = L + (size_t)(i0 + ar) * TWON + kbase + it * 64 + ac;
        a_v0 = *reinterpret_cast<const float4*>(lp);
        a_v1 = *reinterpret_cast<const float4*>(lp + 4);
        a_c0 = *reinterpret_cast<const float4*>(cm + kbase + it * 64 + ac);
        a_c1 = *reinterpret_cast<const float4*>(cm + kbase + it * 64 + ac + 4);
        a_s0 = *reinterpret_cast<const float4*>(rcs + kbase + it * 64 + ac);
        a_s1 = *reinterpret_cast<const float4*>(rcs + kbase + it * 64 + ac + 4);
    };
    auto LOADA1 = [&](int it) {
        const float* lp = L + (size_t)(i0 + ar) * TWON + kbase + it * 64 + ac;
        b_v0 = *reinterpret_cast<const float4*>(lp);
        b_v1 = *reinterpret_cast<const float4*>(lp + 4);
        b_c0 = *reinterpret_cast<const float4*>(cm + kbase + it * 64 + ac);
        b_c1 = *reinterpret_cast<const float4*>(cm + kbase + it * 64 + ac + 4);
        b_s0 = *reinterpret_cast<const float4*>(rcs + kbase + it * 64 + ac);
        b_s1 = *reinterpret_cast<const float4*>(rcs + kbase + it * 64 + ac + 4);
    };
    auto WRITEA0 = [&](int buf) {
        half8 av;
        av[0] = (half_t)(__expf(a_v0.x - hrm - 0.5f * a_c0.x) * sri * a_s0.x);
        av[1] = (half_t)(__expf(a_v0.y - hrm - 0.5f * a_c0.y) * sri * a_s0.y);
        av[2] = (half_t)(__expf(a_v0.z - hrm - 0.5f * a_c0.z) * sri * a_s0.z);
        av[3] = (half_t)(__expf(a_v0.w - hrm - 0.5f * a_c0.w) * sri * a_s0.w);
        av[4] = (half_t)(__expf(a_v1.x - hrm - 0.5f * a_c1.x) * sri * a_s1.x);
        av[5] = (half_t)(__expf(a_v1.y - hrm - 0.5f * a_c1.y) * sri * a_s1.y);
        av[6] = (half_t)(__expf(a_v1.z - hrm - 0.5f * a_c1.z) * sri * a_s1.z);
        av[7] = (half_t)(__expf(a_v1.w - hrm - 0.5f * a_c1.w) * sri * a_s1.w);
        *reinterpret_cast<half8*>(lds + buf * 8192 + awbyte) = av;
    };
    auto WRITEA1 = [&](int buf) {
        half8 av;
        av[0] = (half_t)(__expf(b_v0.x - hrm - 0.5f * b_c0.x) * sri * b_s0.x);
        av[1] = (half_t)(__expf(b_v0.y - hrm - 0.5f * b_c0.y) * sri * b_s0.y);
        av[2] = (half_t)(__expf(b_v0.z - hrm - 0.5f * b_c0.z) * sri * b_s0.z);
        av[3] = (half_t)(__expf(b_v0.w - hrm - 0.5f * b_c0.w) * sri * b_s0.w);
        av[4] = (half_t)(__expf(b_v1.x - hrm - 0.5f * b_c1.x) * sri * b_s1.x);
        av[5] = (half_t)(__expf(b_v1.y - hrm - 0.5f * b_c1.y) * sri * b_s1.y);
        av[6] = (half_t)(__expf(b_v1.z - hrm - 0.5f * b_c1.z) * sri * b_s1.z);
        av[7] = (half_t)(__expf(b_v1.w - hrm - 0.5f * b_c1.w) * sri * b_s1.w);
        *reinterpret_cast<half8*>(lds + buf * 8192 + awbyte) = av;
    };
    auto MFMA_PHASE = [&](int buf, int it) {
        #pragma unroll
        for (int kk = 0; kk < 2; ++kk) {
            half8 af[4], bfr[4];
            #pragma unroll
            for (int m = 0; m < 4; ++m) {
                const int row = m * 16 + (lane & 15);
                const int off = buf * 8192 + row * 128 +
                                ((kk * 64 + (lane >> 4) * 16) ^ ((row & 7) << 4));
                af[m] = *reinterpret_cast<const half8*>(lds + off);
            }
            #pragma unroll
            for (int n = 0; n < 4; ++n) {
                const int d = wn + n * 16 + (lane & 15);
                bfr[n] = *reinterpret_cast<const half8*>(
                    b2t + (size_t)d * TWON + kbase + it * 64 + kk * 32 + (lane >> 4) * 8);
            }
            #pragma unroll
            for (int m = 0; m < 4; ++m)
                #pragma unroll
                for (int n = 0; n < 4; ++n)
                    acc[m][n] = mfma16h(af[m], bfr[n], acc[m][n]);
        }
    };
    LOADA0(0);
    LOADA1(1);
    WRITEA0(0);
    __syncthreads();
    for (int it = 0; it < NT; it += 2) {
        // phase A: compute tile it (buf0); stage tile it+1 (set1->buf1); prefetch it+2 (set0)
        if (it + 2 < NT) LOADA0(it + 2);
        MFMA_PHASE(0, it);
        WRITEA1(1);
        __syncthreads();
        // phase B: compute tile it+1 (buf1); stage tile it+2 (set0->buf0); prefetch it+3 (set1)
        if (it + 3 < NT) LOADA1(it + 3);
        MFMA_PHASE(1, it + 1);
        if (it + 2 < NT) WRITEA0(0);
        __syncthreads();
    }
    float* pout = part + (size_t)kslice * NN * DD;
    #pragma unroll
    for (int m = 0; m < 4; ++m)
        #pragma unroll
        for (int n = 0; n < 4; ++n) {
            const int d = wn + n * 16 + (lane & 15);
            #pragma unroll
            for (int r4 = 0; r4 < 4; ++r4) {
                const int i = i0 + m * 16 + (lane >> 4) * 4 + r4;
                pout[(size_t)i * DD + d] = acc[m][n][r4];
            }
        }
}

// ---------------- reduce partials
__global__ __launch_bounds__(256)
void reduce_k(const float* __restrict__ part, float* __restrict__ out) {
    const size_t e4 = ((size_t)blockIdx.x * 256 + threadIdx.x) * 4;
    float4 a = *reinterpret_cast<const float4*>(part + e4);
    #pragma unroll
    for (int s = 1; s < KSLICE; ++s) {
        float4 b = *reinterpret_cast<const float4*>(part + (size_t)s * NN * DD + e4);
        a.x += b.x; a.y += b.y; a.z += b.z; a.w += b.w;
    }
    *reinterpret_cast<float4*>(out + e4) = a;
}

extern "C" void kernel_launch(void* const* d_in, const int* in_sizes, int n_in,
                              void* d_out, int out_size, void* d_ws, size_t ws_size,
                              hipStream_t stream) {
    const float* x = (const float*)d_in[0];
    const float* y = (const float*)d_in[1];
    float* out = (float*)d_out;

    char* w = (char*)d_ws;
    const size_t OFF_BHI  = 134217728;                 // L ends at 128Mi
    const size_t OFF_BLO  = OFF_BHI + (1u << 23);      // 136Mi (region kept for layout stability)
    const size_t OFF_RPM  = OFF_BLO + (1u << 23);      // 144Mi (gemm1-time)
    const size_t OFF_RPS  = OFF_RPM + (1u << 20);
    const size_t OFF_CPM  = OFF_RPS + (1u << 20);
    const size_t OFF_CPS  = OFF_CPM + (1u << 20);
    const size_t OFF_PART = OFF_BLO;                   // 136Mi..168Mi (gemm2-time)
    const size_t OFF_TAIL = OFF_BLO + (1u << 25);      // 168Mi

    float*  L    = (float*)w;
    half_t* bhi  = (half_t*)(w + OFF_BHI);
    half_t* b2t  = bhi;                                // reuse bhi region after gemm1
    float*  rpm  = (float*)(w + OFF_RPM);
    float*  rps  = (float*)(w + OFF_RPS);
    float*  cpm  = (float*)(w + OFF_CPM);
    float*  cps  = (float*)(w + OFF_CPS);
    float*  part = (float*)(w + OFF_PART);
    float*  nb   = (float*)(w + OFF_TAIL);             // 8192
    float*  rm   = nb  + TWON;                         // 4096
    float*  rrs  = rm  + NN;                           // 4096
    float*  cm   = rrs + NN;                           // 8192
    float*  rcs  = cm  + TWON;                         // 8192

    prep_k<<<TWON, 64, 0, stream>>>(x, y, bhi, nb);
    gemm1_k<<<dim3(TWON / 128, NN / 128), 256, 0, stream>>>(bhi, nb, L,
                                                            rpm, rps, cpm, cps);
    row_comb_k<<<NN / 256, 256, 0, stream>>>(rpm, rps, rm, rrs);
    col_comb_k<<<TWON / 256, 256, 0, stream>>>(cpm, cps, cm, rcs);
    b2t_k<<<dim3(TWON / 32, DD / 32), dim3(32, 8), 0, stream>>>(x, y, b2t);
    gemm2_k<<<256, 512, 0, stream>>>(L, b2t, rm, rrs, cm, rcs, part);
    reduce_k<<<(NN * DD / 4) / 256, 256, 0, stream>>>(part, out);
}